// Round 2
// baseline (30588.351 us; speedup 1.0000x reference)
//
#include <hip/hip_runtime.h>

constexpr int L = 1024;
constexpr int D = 512;      // d_model
constexpr int DI = 1024;    // d_inner
constexpr int DTR = 32;     // dt_rank
constexpr float EPS = 1.1920929e-07f;

__device__ __forceinline__ float siluf(float x) { return x / (1.0f + expf(-x)); }
__device__ __forceinline__ float geluf(float x) { return 0.5f * x * (1.0f + erff(x * 0.7071067811865476f)); }
__device__ __forceinline__ float softplusf(float x) { return fmaxf(x, 0.0f) + log1pf(expf(-fabsf(x))); }

// 8 cubic B-spline bases on the efficient-kan grid (GRID_SIZE=5, order 3)
__device__ __forceinline__ void bspline8(float x, float* o) {
    const float h = 0.4f;
    float g[12];
    #pragma unroll
    for (int j = 0; j < 12; ++j) g[j] = (float)(j - 3) * h - 1.0f;
    float b[11];
    #pragma unroll
    for (int j = 0; j < 11; ++j) b[j] = (x >= g[j] && x < g[j + 1]) ? 1.0f : 0.0f;
    #pragma unroll
    for (int k = 1; k <= 3; ++k) {
        #pragma unroll
        for (int j = 0; j < 11 - k; ++j) {
            float d1 = g[j + k] - g[j];
            float d2 = g[j + k + 1] - g[j + 1];
            b[j] = (x - g[j]) / d1 * b[j] + (g[j + k + 1] - x) / d2 * b[j + 1];
        }
    }
    #pragma unroll
    for (int j = 0; j < 8; ++j) o[j] = b[j];
}

// C[m,n] = act( sum_k A[m,k]*W[n,k] + bias[n] ), A row-major (lda), W row-major (N,K)
// ACT: 0 none, 1 silu, 2 gelu, 3 softplus
template<int ACT>
__global__ __launch_bounds__(256) void gemm_k(
    const float* __restrict__ A, int lda,
    const float* __restrict__ W,
    const float* __restrict__ bias,
    float* __restrict__ C,
    int M, int N, int K)
{
    __shared__ float As[16][68];
    __shared__ float Bs[16][68];
    const int tid = threadIdx.x;
    const int tx = tid & 15, ty = tid >> 4;
    const int m0 = blockIdx.y * 64, n0 = blockIdx.x * 64;
    float acc[4][4] = {};
    for (int k0 = 0; k0 < K; k0 += 16) {
        #pragma unroll
        for (int i = 0; i < 4; ++i) {
            int idx = tid + i * 256;
            int m = idx >> 4, kk = idx & 15;
            As[kk][m] = A[(size_t)(m0 + m) * lda + k0 + kk];
        }
        #pragma unroll
        for (int i = 0; i < 4; ++i) {
            int idx = tid + i * 256;
            int n = idx >> 4, kk = idx & 15;
            Bs[kk][n] = W[(size_t)(n0 + n) * K + k0 + kk];
        }
        __syncthreads();
        #pragma unroll
        for (int kk = 0; kk < 16; ++kk) {
            float a0[4], b0[4];
            #pragma unroll
            for (int i = 0; i < 4; ++i) a0[i] = As[kk][ty * 4 + i];
            #pragma unroll
            for (int j = 0; j < 4; ++j) b0[j] = Bs[kk][tx * 4 + j];
            #pragma unroll
            for (int i = 0; i < 4; ++i)
                #pragma unroll
                for (int j = 0; j < 4; ++j)
                    acc[i][j] += a0[i] * b0[j];
        }
        __syncthreads();
    }
    #pragma unroll
    for (int i = 0; i < 4; ++i) {
        int m = m0 + ty * 4 + i;
        #pragma unroll
        for (int j = 0; j < 4; ++j) {
            int n = n0 + tx * 4 + j;
            float v = acc[i][j];
            if (bias) v += bias[n];
            if (ACT == 1) v = siluf(v);
            else if (ACT == 2) v = geluf(v);
            else if (ACT == 3) v = softplusf(v);
            C[(size_t)m * N + n] = v;
        }
    }
}

// h0[row,d] = silu(x[row])*base_w[d] + sum_j bspl_j(x[row]) * spline_w[d,j]*scaler[d]
__global__ __launch_bounds__(256) void kan_in_k(
    const float* __restrict__ x,
    const float* __restrict__ base_w,
    const float* __restrict__ spline_w,
    const float* __restrict__ scaler,
    float* __restrict__ h0)
{
    int row = blockIdx.x;
    float u = x[row];
    float su = siluf(u);
    float bs[8]; bspline8(u, bs);
    for (int d = threadIdx.x; d < D; d += 256) {
        float s2 = 0.f;
        #pragma unroll
        for (int j = 0; j < 8; ++j) s2 += bs[j] * spline_w[d * 8 + j];
        h0[(size_t)row * D + d] = su * base_w[d] + s2 * scaler[d];
    }
}

// causal depthwise conv (k=4) + bias + silu; src/dst stride DI
__global__ __launch_bounds__(256) void conv_silu_k(
    const float* __restrict__ xc,
    const float* __restrict__ cw,   // (DI,4)
    const float* __restrict__ cb,   // (DI)
    float* __restrict__ out)
{
    int idx = blockIdx.x * 256 + threadIdx.x;   // over Mc*DI
    int d = idx & (DI - 1);
    int row = idx >> 10;
    int s = row & (L - 1);
    float acc = cb[d];
    #pragma unroll
    for (int j = 0; j < 4; ++j) {
        int sp = s + j - 3;
        if (sp >= 0) acc += xc[(size_t)(row + sp - s) * DI + d] * cw[d * 4 + j];
    }
    out[idx] = siluf(acc);
}

// selective scan + D skip + z gate. y aliases z (read-before-write per element, same thread).
__global__ __launch_bounds__(128) void scan_k(
    const float* __restrict__ dt,    // (Mc, DI)
    const float* __restrict__ xca,   // (Mc, DI)
    const float* __restrict__ xdbl,  // (Mc, 64): dt|B|C
    const float* __restrict__ z,     // (Mc, DI)
    const float* __restrict__ A_log, // (DI,16)
    const float* __restrict__ Dp,    // (DI)
    float* __restrict__ y)           // (Mc, DI), == z
{
    const int b = blockIdx.y;
    const int d = blockIdx.x * 128 + threadIdx.x;
    __shared__ float BC[64][32];
    float a[16], h[16];
    #pragma unroll
    for (int n = 0; n < 16; ++n) { a[n] = -expf(A_log[d * 16 + n]); h[n] = 0.f; }
    const float Dd = Dp[d];
    for (int t0 = 0; t0 < L; t0 += 64) {
        __syncthreads();
        for (int i = threadIdx.x; i < 64 * 32; i += 128) {
            int tl = i >> 5, c = i & 31;
            BC[tl][c] = xdbl[(size_t)(b * L + t0 + tl) * 64 + 32 + c];
        }
        __syncthreads();
        for (int tl = 0; tl < 64; ++tl) {
            size_t row = (size_t)(b * L + t0 + tl);
            float dtv = dt[row * DI + d];
            float xv = xca[row * DI + d];
            float zv = z[row * DI + d];
            float dtx = dtv * xv;
            float yv = 0.f;
            #pragma unroll
            for (int n = 0; n < 16; ++n) {
                float dA = expf(dtv * a[n]);
                h[n] = h[n] * dA + dtx * BC[tl][n];
                yv += h[n] * BC[tl][16 + n];
            }
            y[row * DI + d] = (yv + xv * Dd) * siluf(zv);
        }
    }
}

// out[row,:] = rmsnorm(A[row,:]+Bv[row,:]) * w ; one wave per row of 512
__global__ __launch_bounds__(256) void rmsnorm_add_k(
    const float* __restrict__ A,
    const float* __restrict__ Bv,
    const float* __restrict__ w,
    float* __restrict__ out)
{
    int wid = threadIdx.x >> 6, lane = threadIdx.x & 63;
    size_t row = (size_t)blockIdx.x * 4 + wid;
    const float* ar = A + row * D;
    const float* br = Bv + row * D;
    float v[8]; float ss = 0.f;
    #pragma unroll
    for (int i = 0; i < 8; ++i) {
        int c = lane + i * 64;
        float t = ar[c] + br[c];
        v[i] = t; ss += t * t;
    }
    #pragma unroll
    for (int off = 32; off; off >>= 1) ss += __shfl_xor(ss, off);
    float sc = rsqrtf(ss * (1.0f / D) + EPS);
    float* orow = out + row * D;
    #pragma unroll
    for (int i = 0; i < 8; ++i) {
        int c = lane + i * 64;
        orow[c] = v[i] * sc * w[c];
    }
}

// dec[row] = sum_d silu(enc)*bw[d] + sum_{d,j} bspl_j(enc[d])*sw[d,j]*sc[d]; one wave/row
__global__ __launch_bounds__(256) void kan_out_k(
    const float* __restrict__ enc,
    const float* __restrict__ base_w,
    const float* __restrict__ spline_w,
    const float* __restrict__ scaler,
    float* __restrict__ dec)
{
    int wid = threadIdx.x >> 6, lane = threadIdx.x & 63;
    size_t row = (size_t)blockIdx.x * 4 + wid;
    const float* er = enc + row * D;
    float sum = 0.f;
    #pragma unroll
    for (int i = 0; i < 8; ++i) {
        int dd = lane + i * 64;
        float e = er[dd];
        float bs[8]; bspline8(e, bs);
        float s2 = 0.f;
        #pragma unroll
        for (int j = 0; j < 8; ++j) s2 += bs[j] * spline_w[dd * 8 + j];
        sum += siluf(e) * base_w[dd] + s2 * scaler[dd];
    }
    #pragma unroll
    for (int off = 32; off; off >>= 1) sum += __shfl_xor(sum, off);
    if (lane == 0) dec[row] = sum;
}

// out[b,:] = rmsnorm(dec[b,:]+x[b,:]) over SEQ, weight lnx
__global__ __launch_bounds__(256) void final_norm_k(
    const float* __restrict__ dec,
    const float* __restrict__ x,
    const float* __restrict__ w,
    float* __restrict__ out)
{
    int b = blockIdx.x;
    int tid = threadIdx.x;
    __shared__ float wsum[4];
    float v[4]; float ss = 0.f;
    #pragma unroll
    for (int i = 0; i < 4; ++i) {
        int s = tid + i * 256;
        float t = dec[b * L + s] + x[b * L + s];
        v[i] = t; ss += t * t;
    }
    #pragma unroll
    for (int off = 32; off; off >>= 1) ss += __shfl_xor(ss, off);
    int lane = tid & 63, wid = tid >> 6;
    if (lane == 0) wsum[wid] = ss;
    __syncthreads();
    float total = wsum[0] + wsum[1] + wsum[2] + wsum[3];
    float sc = rsqrtf(total * (1.0f / L) + EPS);
    #pragma unroll
    for (int i = 0; i < 4; ++i) {
        int s = tid + i * 256;
        out[b * L + s] = v[i] * sc * w[s];
    }
}

extern "C" void kernel_launch(void* const* d_in, const int* in_sizes, int n_in,
                              void* d_out, int out_size, void* d_ws, size_t ws_size,
                              hipStream_t stream)
{
    const float* x    = (const float*)d_in[0];
    const float* kib  = (const float*)d_in[1];
    const float* kis  = (const float*)d_in[2];
    const float* kic  = (const float*)d_in[3];
    const float* kob  = (const float*)d_in[4];
    const float* kos  = (const float*)d_in[5];
    const float* koc  = (const float*)d_in[6];
    const float* inp  = (const float*)d_in[7];
    const float* cw   = (const float*)d_in[8];
    const float* cb   = (const float*)d_in[9];
    const float* xpw  = (const float*)d_in[10];
    const float* dpw  = (const float*)d_in[11];
    const float* dpb  = (const float*)d_in[12];
    const float* alog = (const float*)d_in[13];
    const float* dpar = (const float*)d_in[14];
    const float* opw  = (const float*)d_in[15];
    const float* w1   = (const float*)d_in[16];
    const float* b1   = (const float*)d_in[17];
    const float* w2   = (const float*)d_in[18];
    const float* b2   = (const float*)d_in[19];
    const float* lnw  = (const float*)d_in[20];
    const float* ln2  = (const float*)d_in[21];
    const float* lnx  = (const float*)d_in[22];

    // pick largest batch-chunk C whose workspace fits
    // per-chunk floats: Mc*(512+512+1024+1024+1024+64+1) = Mc*4161, Mc = C*1024
    int C = 32;
    while (C > 1 && (size_t)C * 1024 * 4161 * sizeof(float) > ws_size) C >>= 1;
    if ((size_t)C * 1024 * 4161 * sizeof(float) > ws_size) return;

    for (int b0 = 0; b0 < 32; b0 += C) {
        const size_t Mc = (size_t)C * L;
        float* ws   = (float*)d_ws;
        float* h0   = ws;  ws += Mc * D;       // residual2 (persistent in chunk)
        float* hcur = ws;  ws += Mc * D;       // running hidden state
        float* bufA = ws;  ws += Mc * DI;      // xc -> dt -> hm(512) | mlp_out(512)
        float* bufB = ws;  ws += Mc * DI;      // xca -> hid
        float* bufZ = ws;  ws += Mc * DI;      // z -> y (in place)
        float* xdbl = ws;  ws += Mc * 64;
        float* dec  = ws;  ws += Mc;

        kan_in_k<<<(unsigned)Mc, 256, 0, stream>>>(x + (size_t)b0 * L, kib, kis, kic, h0);

        for (int l = 0; l < 4; ++l) {
            const float* hin = (l == 0) ? h0 : hcur;
            const float* inp_l = inp + (size_t)l * 2 * DI * D;
            // xc = hin @ in_proj[:DI]^T -> bufA ; z = hin @ in_proj[DI:]^T -> bufZ
            gemm_k<0><<<dim3(DI / 64, (unsigned)(Mc / 64)), 256, 0, stream>>>(
                hin, D, inp_l, nullptr, bufA, (int)Mc, DI, D);
            gemm_k<0><<<dim3(DI / 64, (unsigned)(Mc / 64)), 256, 0, stream>>>(
                hin, D, inp_l + (size_t)DI * D, nullptr, bufZ, (int)Mc, DI, D);
            // xca = silu(causal_conv(xc)) -> bufB
            conv_silu_k<<<(unsigned)((Mc * DI) / 256), 256, 0, stream>>>(
                bufA, cw + (size_t)l * DI * 4, cb + (size_t)l * DI, bufB);
            // xdbl = xca @ x_proj^T  (Mc, 64)
            gemm_k<0><<<dim3(1, (unsigned)(Mc / 64)), 256, 0, stream>>>(
                bufB, DI, xpw + (size_t)l * 64 * DI, nullptr, xdbl, (int)Mc, 64, DI);
            // dt = softplus(xdbl[:, :32] @ dt_proj^T + b) -> bufA (xc dead after conv)
            gemm_k<3><<<dim3(DI / 64, (unsigned)(Mc / 64)), 256, 0, stream>>>(
                xdbl, 64, dpw + (size_t)l * DI * DTR, dpb + (size_t)l * DI, bufA, (int)Mc, DI, DTR);
            // selective scan + D skip + z gate -> y in place over z (bufZ)
            scan_k<<<dim3(DI / 128, C), 128, 0, stream>>>(
                bufA, bufB, xdbl, bufZ, alog + (size_t)l * DI * 16, dpar + (size_t)l * DI, bufZ);
            // hm = y @ out_proj^T (Mc, 512) -> bufA[0 : Mc*512]
            gemm_k<0><<<dim3(D / 64, (unsigned)(Mc / 64)), 256, 0, stream>>>(
                bufZ, DI, opw + (size_t)l * D * DI, nullptr, bufA, (int)Mc, D, DI);
            // hid = gelu(hm @ w1^T + b1) (Mc, 1024) -> bufB
            gemm_k<2><<<dim3(DI / 64, (unsigned)(Mc / 64)), 256, 0, stream>>>(
                bufA, D, w1, b1, bufB, (int)Mc, DI, D);
            // mlp = gelu(hid @ w2^T + b2) (Mc, 512) -> bufA[Mc*512 : Mc*1024]
            gemm_k<2><<<dim3(D / 64, (unsigned)(Mc / 64)), 256, 0, stream>>>(
                bufB, DI, w2, b2, bufA + Mc * D, (int)Mc, D, DI);
            // hcur = rmsnorm(mlp + hin) * ln_w
            rmsnorm_add_k<<<(unsigned)(Mc / 4), 256, 0, stream>>>(bufA + Mc * D, hin, lnw, hcur);
        }
        // enc = rmsnorm(hcur + h0) * ln2  (in place)
        rmsnorm_add_k<<<(unsigned)(Mc / 4), 256, 0, stream>>>(hcur, h0, ln2, hcur);
        // dec[row] = kan_out(enc[row,:])
        kan_out_k<<<(unsigned)(Mc / 4), 256, 0, stream>>>(hcur, kob, kos, koc, dec);
        // out = rmsnorm(dec + x) * lnx over SEQ
        final_norm_k<<<C, 256, 0, stream>>>(dec, x + (size_t)b0 * L, lnx, (float*)d_out + (size_t)b0 * L);
    }
}

// Round 3
// 20848.866 us; speedup vs baseline: 1.4671x; 1.4671x over previous
//
#include <hip/hip_runtime.h>

constexpr int L = 1024;
constexpr int D = 512;      // d_model
constexpr int DI = 1024;    // d_inner
constexpr float EPS = 1.1920929e-07f;

__device__ __forceinline__ float siluf(float x) { return x / (1.0f + expf(-x)); }
__device__ __forceinline__ float geluf(float x) { return 0.5f * x * (1.0f + erff(x * 0.7071067811865476f)); }
__device__ __forceinline__ float softplusf(float x) { return fmaxf(x, 0.0f) + log1pf(expf(-fabsf(x))); }

// 8 cubic B-spline bases on the efficient-kan grid (GRID_SIZE=5, order 3)
__device__ __forceinline__ void bspline8(float x, float* o) {
    const float h = 0.4f;
    float g[12];
    #pragma unroll
    for (int j = 0; j < 12; ++j) g[j] = (float)(j - 3) * h - 1.0f;
    float b[11];
    #pragma unroll
    for (int j = 0; j < 11; ++j) b[j] = (x >= g[j] && x < g[j + 1]) ? 1.0f : 0.0f;
    #pragma unroll
    for (int k = 1; k <= 3; ++k) {
        #pragma unroll
        for (int j = 0; j < 11 - k; ++j) {
            float d1 = g[j + k] - g[j];
            float d2 = g[j + k + 1] - g[j + 1];
            b[j] = (x - g[j]) / d1 * b[j] + (g[j + k + 1] - x) / d2 * b[j + 1];
        }
    }
    #pragma unroll
    for (int j = 0; j < 8; ++j) o[j] = b[j];
}

// C[m,n] = act( sum_k A[m,k]*W[n,k] + bias[n] ), A row-major (lda), W row-major (N,K)
template<int ACT>
__global__ __launch_bounds__(256) void gemm_k(
    const float* __restrict__ A, int lda,
    const float* __restrict__ W,
    const float* __restrict__ bias,
    float* __restrict__ C,
    int M, int N, int K)
{
    __shared__ float As[16][68];
    __shared__ float Bs[16][68];
    const int tid = threadIdx.x;
    const int tx = tid & 15, ty = tid >> 4;
    const int m0 = blockIdx.y * 64, n0 = blockIdx.x * 64;
    float acc[4][4] = {};
    for (int k0 = 0; k0 < K; k0 += 16) {
        #pragma unroll
        for (int i = 0; i < 4; ++i) {
            int idx = tid + i * 256;
            int m = idx >> 4, kk = idx & 15;
            As[kk][m] = A[(size_t)(m0 + m) * lda + k0 + kk];
        }
        #pragma unroll
        for (int i = 0; i < 4; ++i) {
            int idx = tid + i * 256;
            int n = idx >> 4, kk = idx & 15;
            Bs[kk][n] = W[(size_t)(n0 + n) * K + k0 + kk];
        }
        __syncthreads();
        #pragma unroll
        for (int kk = 0; kk < 16; ++kk) {
            float a0[4], b0[4];
            #pragma unroll
            for (int i = 0; i < 4; ++i) a0[i] = As[kk][ty * 4 + i];
            #pragma unroll
            for (int j = 0; j < 4; ++j) b0[j] = Bs[kk][tx * 4 + j];
            #pragma unroll
            for (int i = 0; i < 4; ++i)
                #pragma unroll
                for (int j = 0; j < 4; ++j)
                    acc[i][j] += a0[i] * b0[j];
        }
        __syncthreads();
    }
    #pragma unroll
    for (int i = 0; i < 4; ++i) {
        int m = m0 + ty * 4 + i;
        #pragma unroll
        for (int j = 0; j < 4; ++j) {
            int n = n0 + tx * 4 + j;
            float v = acc[i][j];
            if (bias) v += bias[n];
            if (ACT == 1) v = siluf(v);
            else if (ACT == 2) v = geluf(v);
            C[(size_t)m * N + n] = v;
        }
    }
}

// Same GEMM but A is stored "time-major": logical A(m,k) with m=(b,l), b=m/L, l=m%L,
// element at At[(b*K + k)*L + l].  (K = DI for all users.)
template<int ACT>
__global__ __launch_bounds__(256) void gemm_at_k(
    const float* __restrict__ At,
    const float* __restrict__ W,
    const float* __restrict__ bias,
    float* __restrict__ C,
    int M, int N, int K)
{
    __shared__ float As[16][68];
    __shared__ float Bs[16][68];
    const int tid = threadIdx.x;
    const int tx = tid & 15, ty = tid >> 4;
    const int m0 = blockIdx.y * 64, n0 = blockIdx.x * 64;
    const int b = m0 >> 10;          // m0 / L, 64-row block lies within one b
    const int l0 = m0 & (L - 1);
    float acc[4][4] = {};
    for (int k0 = 0; k0 < K; k0 += 16) {
        #pragma unroll
        for (int i = 0; i < 4; ++i) {
            int idx = tid + i * 256;
            int kk = idx >> 6, ml = idx & 63;
            As[kk][ml] = At[((size_t)b * K + k0 + kk) * L + l0 + ml];
        }
        #pragma unroll
        for (int i = 0; i < 4; ++i) {
            int idx = tid + i * 256;
            int n = idx >> 4, kk = idx & 15;
            Bs[kk][n] = W[(size_t)(n0 + n) * K + k0 + kk];
        }
        __syncthreads();
        #pragma unroll
        for (int kk = 0; kk < 16; ++kk) {
            float a0[4], b0[4];
            #pragma unroll
            for (int i = 0; i < 4; ++i) a0[i] = As[kk][ty * 4 + i];
            #pragma unroll
            for (int j = 0; j < 4; ++j) b0[j] = Bs[kk][tx * 4 + j];
            #pragma unroll
            for (int i = 0; i < 4; ++i)
                #pragma unroll
                for (int j = 0; j < 4; ++j)
                    acc[i][j] += a0[i] * b0[j];
        }
        __syncthreads();
    }
    #pragma unroll
    for (int i = 0; i < 4; ++i) {
        int m = m0 + ty * 4 + i;
        #pragma unroll
        for (int j = 0; j < 4; ++j) {
            int n = n0 + tx * 4 + j;
            float v = acc[i][j];
            if (bias) v += bias[n];
            if (ACT == 1) v = siluf(v);
            else if (ACT == 2) v = geluf(v);
            C[(size_t)m * N + n] = v;
        }
    }
}

// h0[row,d] = silu(x[row])*base_w[d] + sum_j bspl_j(x[row]) * spline_w[d,j]*scaler[d]
__global__ __launch_bounds__(256) void kan_in_k(
    const float* __restrict__ x,
    const float* __restrict__ base_w,
    const float* __restrict__ spline_w,
    const float* __restrict__ scaler,
    float* __restrict__ h0)
{
    int row = blockIdx.x;
    float u = x[row];
    float su = siluf(u);
    float bs[8]; bspline8(u, bs);
    for (int d = threadIdx.x; d < D; d += 256) {
        float s2 = 0.f;
        #pragma unroll
        for (int j = 0; j < 8; ++j) s2 += bs[j] * spline_w[d * 8 + j];
        h0[(size_t)row * D + d] = su * base_w[d] + s2 * scaler[d];
    }
}

// causal depthwise conv (k=4) + bias + silu; reads xc (Mc, DI) row-major,
// writes time-major xca_t[(b*DI + d)*L + t].  Tile: 64 t x 64 d, LDS transpose.
__global__ __launch_bounds__(256) void conv_tr_k(
    const float* __restrict__ xc,
    const float* __restrict__ cw,   // (DI,4)
    const float* __restrict__ cb,   // (DI)
    float* __restrict__ xca_t)
{
    const int b = blockIdx.z;
    const int t0 = blockIdx.y * 64;
    const int d0 = blockIdx.x * 64;
    const int tid = threadIdx.x;
    __shared__ float xs[67][65];
    #pragma unroll
    for (int i = 0; i < 17; ++i) {
        int idx = tid + i * 256;
        if (idx < 67 * 64) {
            int r = idx >> 6, c = idx & 63;
            int t = t0 - 3 + r;
            xs[r][c] = (t >= 0) ? xc[((size_t)b * L + t) * DI + d0 + c] : 0.0f;
        }
    }
    __syncthreads();
    const int dl = tid >> 2, seg = tid & 3;
    float w[4], out[16];
    #pragma unroll
    for (int j = 0; j < 4; ++j) w[j] = cw[(d0 + dl) * 4 + j];
    const float bias = cb[d0 + dl];
    #pragma unroll
    for (int u = 0; u < 16; ++u) {
        int tl = seg * 16 + u;
        float acc = bias;
        #pragma unroll
        for (int j = 0; j < 4; ++j) acc += xs[tl + j][dl] * w[j];
        out[u] = siluf(acc);
    }
    float* dst = xca_t + ((size_t)b * DI + d0 + dl) * L + t0 + seg * 16;
    #pragma unroll
    for (int u = 0; u < 4; ++u)
        *reinterpret_cast<float4*>(dst + u * 4) = make_float4(out[u*4], out[u*4+1], out[u*4+2], out[u*4+3]);
}

// Fused selective scan: computes dt from xdbl (LDS) + dt_proj, scans 16 states
// (4 per lane across a 4-lane quad), applies D-skip and silu(z) gate, writes
// gated y in time-major layout.  Block: 256 threads = 64 d x 4 subs, one b.
__global__ __launch_bounds__(256) void scan_fused_k(
    const float* __restrict__ xca_t, // (C, DI, L)
    const float* __restrict__ xdbl,  // (Mc, 64): dtproj-in | B | C
    const float* __restrict__ z,     // (Mc, DI)
    const float* __restrict__ dpw,   // (DI, 32)
    const float* __restrict__ dpb,   // (DI)
    const float* __restrict__ A_log, // (DI, 16)
    const float* __restrict__ Dp,    // (DI)
    float* __restrict__ y_t)         // (C, DI, L) gated output
{
    const int b = blockIdx.y;
    const int d0 = blockIdx.x * 64;
    const int tid = threadIdx.x;
    const int dl = tid >> 2, sub = tid & 3;
    const int d = d0 + dl;

    __shared__ float xdbl_s[64][68];
    __shared__ float xca_s[64][65];  // [d][t]
    __shared__ float z_s[64][65];    // [t][d]

    float dpwr[8], a[4], h[4];
    #pragma unroll
    for (int j = 0; j < 8; ++j) dpwr[j] = dpw[d * 32 + 8 * sub + j];
    #pragma unroll
    for (int i = 0; i < 4; ++i) { a[i] = -expf(A_log[d * 16 + 4 * sub + i]); h[i] = 0.f; }
    const float dpbd = dpb[d];
    const float Dd = Dp[d];

    for (int t0 = 0; t0 < L; t0 += 64) {
        // stage xdbl (64t x 64), xca (64d x 64t), z (64t x 64d) — all coalesced
        #pragma unroll
        for (int i = 0; i < 16; ++i) {
            int idx = tid + i * 256;
            int r = idx >> 6, c = idx & 63;
            xdbl_s[r][c] = xdbl[((size_t)b * L + t0 + r) * 64 + c];
        }
        #pragma unroll
        for (int i = 0; i < 16; ++i) {
            int idx = tid + i * 256;
            int r = idx >> 6, c = idx & 63;   // r = d_local, c = t_local
            xca_s[r][c] = xca_t[((size_t)b * DI + d0 + r) * L + t0 + c];
        }
        #pragma unroll
        for (int i = 0; i < 16; ++i) {
            int idx = tid + i * 256;
            int r = idx >> 6, c = idx & 63;   // r = t_local, c = d_local
            z_s[r][c] = z[((size_t)b * L + t0 + r) * DI + d0 + c];
        }
        __syncthreads();

        for (int tl4 = 0; tl4 < 16; ++tl4) {
            float yhold = 0.f;
            #pragma unroll
            for (int uu = 0; uu < 4; ++uu) {
                int tl = tl4 * 4 + uu;
                // dt = softplus(xdbl[t,0:32] . dpw[d,:] + dpb[d]) — 8 terms/lane + quad reduce
                float pdt = 0.f;
                #pragma unroll
                for (int j = 0; j < 8; ++j) pdt += xdbl_s[tl][8 * sub + j] * dpwr[j];
                pdt += __shfl_xor(pdt, 1);
                pdt += __shfl_xor(pdt, 2);
                float dtv = softplusf(pdt + dpbd);
                float xv = xca_s[dl][tl];
                float zv = z_s[tl][dl];
                float dtx = dtv * xv;
                float yv = 0.f;
                #pragma unroll
                for (int i = 0; i < 4; ++i) {
                    float dA = expf(dtv * a[i]);
                    h[i] = h[i] * dA + dtx * xdbl_s[tl][32 + 4 * sub + i];
                    yv += h[i] * xdbl_s[tl][48 + 4 * sub + i];
                }
                yv += __shfl_xor(yv, 1);
                yv += __shfl_xor(yv, 2);
                float yout = (yv + xv * Dd) * siluf(zv);
                if (uu == sub) yhold = yout;
            }
            y_t[((size_t)b * DI + d) * L + t0 + tl4 * 4 + sub] = yhold;
        }
        __syncthreads();
    }
}

// out[row,:] = rmsnorm(A[row,:]+Bv[row,:]) * w ; one wave per row of 512
__global__ __launch_bounds__(256) void rmsnorm_add_k(
    const float* __restrict__ A,
    const float* __restrict__ Bv,
    const float* __restrict__ w,
    float* __restrict__ out)
{
    int wid = threadIdx.x >> 6, lane = threadIdx.x & 63;
    size_t row = (size_t)blockIdx.x * 4 + wid;
    const float* ar = A + row * D;
    const float* br = Bv + row * D;
    float v[8]; float ss = 0.f;
    #pragma unroll
    for (int i = 0; i < 8; ++i) {
        int c = lane + i * 64;
        float t = ar[c] + br[c];
        v[i] = t; ss += t * t;
    }
    #pragma unroll
    for (int off = 32; off; off >>= 1) ss += __shfl_xor(ss, off);
    float sc = rsqrtf(ss * (1.0f / D) + EPS);
    float* orow = out + row * D;
    #pragma unroll
    for (int i = 0; i < 8; ++i) {
        int c = lane + i * 64;
        orow[c] = v[i] * sc * w[c];
    }
}

// dec[row] = sum_d silu(enc)*bw[d] + sum_{d,j} bspl_j(enc[d])*sw[d,j]*sc[d]; one wave/row
__global__ __launch_bounds__(256) void kan_out_k(
    const float* __restrict__ enc,
    const float* __restrict__ base_w,
    const float* __restrict__ spline_w,
    const float* __restrict__ scaler,
    float* __restrict__ dec)
{
    int wid = threadIdx.x >> 6, lane = threadIdx.x & 63;
    size_t row = (size_t)blockIdx.x * 4 + wid;
    const float* er = enc + row * D;
    float sum = 0.f;
    #pragma unroll
    for (int i = 0; i < 8; ++i) {
        int dd = lane + i * 64;
        float e = er[dd];
        float bs[8]; bspline8(e, bs);
        float s2 = 0.f;
        #pragma unroll
        for (int j = 0; j < 8; ++j) s2 += bs[j] * spline_w[dd * 8 + j];
        sum += siluf(e) * base_w[dd] + s2 * scaler[dd];
    }
    #pragma unroll
    for (int off = 32; off; off >>= 1) sum += __shfl_xor(sum, off);
    if (lane == 0) dec[row] = sum;
}

// out[b,:] = rmsnorm(dec[b,:]+x[b,:]) over SEQ, weight lnx
__global__ __launch_bounds__(256) void final_norm_k(
    const float* __restrict__ dec,
    const float* __restrict__ x,
    const float* __restrict__ w,
    float* __restrict__ out)
{
    int b = blockIdx.x;
    int tid = threadIdx.x;
    __shared__ float wsum[4];
    float v[4]; float ss = 0.f;
    #pragma unroll
    for (int i = 0; i < 4; ++i) {
        int s = tid + i * 256;
        float t = dec[b * L + s] + x[b * L + s];
        v[i] = t; ss += t * t;
    }
    #pragma unroll
    for (int off = 32; off; off >>= 1) ss += __shfl_xor(ss, off);
    int lane = tid & 63, wid = tid >> 6;
    if (lane == 0) wsum[wid] = ss;
    __syncthreads();
    float total = wsum[0] + wsum[1] + wsum[2] + wsum[3];
    float sc = rsqrtf(total * (1.0f / L) + EPS);
    #pragma unroll
    for (int i = 0; i < 4; ++i) {
        int s = tid + i * 256;
        out[b * L + s] = v[i] * sc * w[s];
    }
}

extern "C" void kernel_launch(void* const* d_in, const int* in_sizes, int n_in,
                              void* d_out, int out_size, void* d_ws, size_t ws_size,
                              hipStream_t stream)
{
    const float* x    = (const float*)d_in[0];
    const float* kib  = (const float*)d_in[1];
    const float* kis  = (const float*)d_in[2];
    const float* kic  = (const float*)d_in[3];
    const float* kob  = (const float*)d_in[4];
    const float* kos  = (const float*)d_in[5];
    const float* koc  = (const float*)d_in[6];
    const float* inp  = (const float*)d_in[7];
    const float* cw   = (const float*)d_in[8];
    const float* cb   = (const float*)d_in[9];
    const float* xpw  = (const float*)d_in[10];
    const float* dpw  = (const float*)d_in[11];
    const float* dpb  = (const float*)d_in[12];
    const float* alog = (const float*)d_in[13];
    const float* dpar = (const float*)d_in[14];
    const float* opw  = (const float*)d_in[15];
    const float* w1   = (const float*)d_in[16];
    const float* b1   = (const float*)d_in[17];
    const float* w2   = (const float*)d_in[18];
    const float* b2   = (const float*)d_in[19];
    const float* lnw  = (const float*)d_in[20];
    const float* ln2  = (const float*)d_in[21];
    const float* lnx  = (const float*)d_in[22];

    // per-chunk floats: Mc*(512+512+1024+1024+1024+64+1) = Mc*4161, Mc = C*1024
    int C = 32;
    while (C > 1 && (size_t)C * 1024 * 4161 * sizeof(float) > ws_size) C >>= 1;
    if ((size_t)C * 1024 * 4161 * sizeof(float) > ws_size) return;

    for (int b0 = 0; b0 < 32; b0 += C) {
        const size_t Mc = (size_t)C * L;
        float* ws   = (float*)d_ws;
        float* h0   = ws;  ws += Mc * D;       // residual2
        float* hcur = ws;  ws += Mc * D;       // running hidden
        float* bufA = ws;  ws += Mc * DI;      // xc (row-major) -> y_gated_t
        float* bufB = ws;  ws += Mc * DI;      // xca_t -> hm(512) | mlp_out(512)
        float* bufZ = ws;  ws += Mc * DI;      // z -> hid
        float* xdbl = ws;  ws += Mc * 64;
        float* dec  = ws;  ws += Mc;

        kan_in_k<<<(unsigned)Mc, 256, 0, stream>>>(x + (size_t)b0 * L, kib, kis, kic, h0);

        for (int l = 0; l < 4; ++l) {
            const float* hin = (l == 0) ? h0 : hcur;
            const float* inp_l = inp + (size_t)l * 2 * DI * D;
            // xc = hin @ Wxc^T -> bufA ; z = hin @ Wz^T -> bufZ
            gemm_k<0><<<dim3(DI / 64, (unsigned)(Mc / 64)), 256, 0, stream>>>(
                hin, D, inp_l, nullptr, bufA, (int)Mc, DI, D);
            gemm_k<0><<<dim3(DI / 64, (unsigned)(Mc / 64)), 256, 0, stream>>>(
                hin, D, inp_l + (size_t)DI * D, nullptr, bufZ, (int)Mc, DI, D);
            // xca_t = silu(causal_conv(xc)), time-major -> bufB
            conv_tr_k<<<dim3(DI / 64, L / 64, C), 256, 0, stream>>>(
                bufA, cw + (size_t)l * DI * 4, cb + (size_t)l * DI, bufB);
            // xdbl = xca @ x_proj^T  (Mc, 64)
            gemm_at_k<0><<<dim3(1, (unsigned)(Mc / 64)), 256, 0, stream>>>(
                bufB, xpw + (size_t)l * 64 * DI, nullptr, xdbl, (int)Mc, 64, DI);
            // fused scan: dt-proj + scan + D-skip + silu(z) gate -> y_gated_t in bufA
            scan_fused_k<<<dim3(DI / 64, C), 256, 0, stream>>>(
                bufB, xdbl, bufZ,
                dpw + (size_t)l * DI * 32, dpb + (size_t)l * DI,
                alog + (size_t)l * DI * 16, dpar + (size_t)l * DI, bufA);
            // hm = y_gated @ out_proj^T (Mc, 512) -> bufB (xca_t dead)
            gemm_at_k<0><<<dim3(D / 64, (unsigned)(Mc / 64)), 256, 0, stream>>>(
                bufA, opw + (size_t)l * D * DI, nullptr, bufB, (int)Mc, D, DI);
            // hid = gelu(hm @ w1^T + b1) (Mc, 1024) -> bufZ (z dead)
            gemm_k<2><<<dim3(DI / 64, (unsigned)(Mc / 64)), 256, 0, stream>>>(
                bufB, D, w1, b1, bufZ, (int)Mc, DI, D);
            // mlp = gelu(hid @ w2^T + b2) (Mc, 512) -> bufB second half (hm dead)
            gemm_k<2><<<dim3(D / 64, (unsigned)(Mc / 64)), 256, 0, stream>>>(
                bufZ, DI, w2, b2, bufB + Mc * D, (int)Mc, D, DI);
            // hcur = rmsnorm(mlp + hin) * ln_w
            rmsnorm_add_k<<<(unsigned)(Mc / 4), 256, 0, stream>>>(bufB + Mc * D, hin, lnw, hcur);
        }
        // enc = rmsnorm(hcur + h0) * ln2  (in place)
        rmsnorm_add_k<<<(unsigned)(Mc / 4), 256, 0, stream>>>(hcur, h0, ln2, hcur);
        kan_out_k<<<(unsigned)(Mc / 4), 256, 0, stream>>>(hcur, kob, kos, koc, dec);
        final_norm_k<<<C, 256, 0, stream>>>(dec, x + (size_t)b0 * L, lnx, (float*)d_out + (size_t)b0 * L);
    }
}

// Round 4
// 6726.431 us; speedup vs baseline: 4.5475x; 3.0995x over previous
//
#include <hip/hip_runtime.h>

constexpr int L = 1024;
constexpr int D = 512;      // d_model
constexpr int DI = 1024;    // d_inner
constexpr float EPS = 1.1920929e-07f;

typedef short bf16x8 __attribute__((ext_vector_type(8)));
typedef float f32x4 __attribute__((ext_vector_type(4)));

__device__ __forceinline__ float siluf(float x) { return x / (1.0f + expf(-x)); }
__device__ __forceinline__ float geluf(float x) { return 0.5f * x * (1.0f + erff(x * 0.7071067811865476f)); }
__device__ __forceinline__ float softplusf(float x) { return fmaxf(x, 0.0f) + log1pf(expf(-fabsf(x))); }

__device__ __forceinline__ float bf2f(ushort h) {
    unsigned u = ((unsigned)h) << 16;
    return __uint_as_float(u);
}
__device__ __forceinline__ ushort f2bf(float f) {
    unsigned u = __float_as_uint(f);
    u = (u + 0x7fffu + ((u >> 16) & 1u)) >> 16;
    return (ushort)u;
}

// 8 cubic B-spline bases on the efficient-kan grid (GRID_SIZE=5, order 3)
__device__ __forceinline__ void bspline8(float x, float* o) {
    const float h = 0.4f;
    float g[12];
    #pragma unroll
    for (int j = 0; j < 12; ++j) g[j] = (float)(j - 3) * h - 1.0f;
    float b[11];
    #pragma unroll
    for (int j = 0; j < 11; ++j) b[j] = (x >= g[j] && x < g[j + 1]) ? 1.0f : 0.0f;
    #pragma unroll
    for (int k = 1; k <= 3; ++k) {
        #pragma unroll
        for (int j = 0; j < 11 - k; ++j) {
            float d1 = g[j + k] - g[j];
            float d2 = g[j + k + 1] - g[j + 1];
            b[j] = (x - g[j]) / d1 * b[j] + (g[j + k + 1] - x) / d2 * b[j + 1];
        }
    }
    #pragma unroll
    for (int j = 0; j < 8; ++j) o[j] = b[j];
}

// fp32 -> bf16 convert (weights), grid-stride
__global__ __launch_bounds__(256) void cvt_bf16_k(const float* __restrict__ s,
                                                  ushort* __restrict__ d, int n) {
    for (int i = blockIdx.x * 256 + threadIdx.x; i < n; i += gridDim.x * 256)
        d[i] = f2bf(s[i]);
}

// MFMA GEMM: C[m,n] = act( sum_k A[m,k]*W[n,k] + bias[n] )
// A: fp32 (A_F32=1) or bf16; W: bf16 (N,K); C: bf16 (OUT_BF16=1) or fp32.
// Tile 128x64, K-step 32, 4 waves; wave w owns rows [w*32, w*32+32).
// ACT: 0 none, 2 gelu
template<int ACT, int A_F32, int OUT_BF16>
__global__ __launch_bounds__(256) void gemm_mfma_k(
    const void* __restrict__ Av, int lda,
    const ushort* __restrict__ W,
    const float* __restrict__ bias,
    void* __restrict__ Cv,
    int M, int N, int K)
{
    __shared__ __align__(16) ushort As[128][40];
    __shared__ __align__(16) ushort Bs[64][40];
    const int tid = threadIdx.x;
    const int m0 = blockIdx.y * 128, n0 = blockIdx.x * 64;
    const int w = tid >> 6, lane = tid & 63;
    const int lr = lane & 15, lh = lane >> 4;
    const int arow = tid >> 1, akoff = (tid & 1) * 16;   // A: 2 thr/row, 16 el each
    const int brow = tid >> 2, bkoff = (tid & 3) * 8;    // B: 4 thr/row, 8 el each

    f32x4 acc[2][4] = {};

    for (int k0 = 0; k0 < K; k0 += 32) {
        if (A_F32) {
            const float* Ar = (const float*)Av + (size_t)(m0 + arow) * lda + k0 + akoff;
            f32x4 q0 = *(const f32x4*)(Ar);
            f32x4 q1 = *(const f32x4*)(Ar + 4);
            f32x4 q2 = *(const f32x4*)(Ar + 8);
            f32x4 q3 = *(const f32x4*)(Ar + 12);
            ushort* dst = &As[arow][akoff];
            dst[0] = f2bf(q0[0]); dst[1] = f2bf(q0[1]); dst[2] = f2bf(q0[2]); dst[3] = f2bf(q0[3]);
            dst[4] = f2bf(q1[0]); dst[5] = f2bf(q1[1]); dst[6] = f2bf(q1[2]); dst[7] = f2bf(q1[3]);
            dst[8] = f2bf(q2[0]); dst[9] = f2bf(q2[1]); dst[10] = f2bf(q2[2]); dst[11] = f2bf(q2[3]);
            dst[12] = f2bf(q3[0]); dst[13] = f2bf(q3[1]); dst[14] = f2bf(q3[2]); dst[15] = f2bf(q3[3]);
        } else {
            const ushort* Ar = (const ushort*)Av + (size_t)(m0 + arow) * lda + k0 + akoff;
            *(bf16x8*)&As[arow][akoff] = *(const bf16x8*)Ar;
            *(bf16x8*)&As[arow][akoff + 8] = *(const bf16x8*)(Ar + 8);
        }
        const ushort* Wr = W + (size_t)(n0 + brow) * K + k0 + bkoff;
        *(bf16x8*)&Bs[brow][bkoff] = *(const bf16x8*)Wr;
        __syncthreads();

        bf16x8 aF0 = *(bf16x8*)&As[w * 32 + lr][lh * 8];
        bf16x8 aF1 = *(bf16x8*)&As[w * 32 + 16 + lr][lh * 8];
        bf16x8 bF0 = *(bf16x8*)&Bs[lr][lh * 8];
        bf16x8 bF1 = *(bf16x8*)&Bs[16 + lr][lh * 8];
        bf16x8 bF2 = *(bf16x8*)&Bs[32 + lr][lh * 8];
        bf16x8 bF3 = *(bf16x8*)&Bs[48 + lr][lh * 8];
        acc[0][0] = __builtin_amdgcn_mfma_f32_16x16x32_bf16(aF0, bF0, acc[0][0], 0, 0, 0);
        acc[0][1] = __builtin_amdgcn_mfma_f32_16x16x32_bf16(aF0, bF1, acc[0][1], 0, 0, 0);
        acc[0][2] = __builtin_amdgcn_mfma_f32_16x16x32_bf16(aF0, bF2, acc[0][2], 0, 0, 0);
        acc[0][3] = __builtin_amdgcn_mfma_f32_16x16x32_bf16(aF0, bF3, acc[0][3], 0, 0, 0);
        acc[1][0] = __builtin_amdgcn_mfma_f32_16x16x32_bf16(aF1, bF0, acc[1][0], 0, 0, 0);
        acc[1][1] = __builtin_amdgcn_mfma_f32_16x16x32_bf16(aF1, bF1, acc[1][1], 0, 0, 0);
        acc[1][2] = __builtin_amdgcn_mfma_f32_16x16x32_bf16(aF1, bF2, acc[1][2], 0, 0, 0);
        acc[1][3] = __builtin_amdgcn_mfma_f32_16x16x32_bf16(aF1, bF3, acc[1][3], 0, 0, 0);
        __syncthreads();
    }

    #pragma unroll
    for (int mi = 0; mi < 2; ++mi) {
        #pragma unroll
        for (int nj = 0; nj < 4; ++nj) {
            int col = n0 + nj * 16 + lr;
            float bv = bias ? bias[col] : 0.0f;
            int rbase = m0 + w * 32 + mi * 16 + lh * 4;
            #pragma unroll
            for (int r = 0; r < 4; ++r) {
                float v = acc[mi][nj][r] + bv;
                if (ACT == 2) v = geluf(v);
                if (OUT_BF16) ((ushort*)Cv)[(size_t)(rbase + r) * N + col] = f2bf(v);
                else          ((float*)Cv)[(size_t)(rbase + r) * N + col] = v;
            }
        }
    }
}

// h0[row,d] = silu(x[row])*base_w[d] + sum_j bspl_j(x[row]) * spline_w[d,j]*scaler[d]
__global__ __launch_bounds__(256) void kan_in_k(
    const float* __restrict__ x,
    const float* __restrict__ base_w,
    const float* __restrict__ spline_w,
    const float* __restrict__ scaler,
    float* __restrict__ h0)
{
    int row = blockIdx.x;
    float u = x[row];
    float su = siluf(u);
    float bs[8]; bspline8(u, bs);
    for (int d = threadIdx.x; d < D; d += 256) {
        float s2 = 0.f;
        #pragma unroll
        for (int j = 0; j < 8; ++j) s2 += bs[j] * spline_w[d * 8 + j];
        h0[(size_t)row * D + d] = su * base_w[d] + s2 * scaler[d];
    }
}

// causal depthwise conv (k=4) + bias + silu; bf16 in/out, row-major (Mc, DI)
__global__ __launch_bounds__(256) void conv_silu_k(
    const ushort* __restrict__ xc,
    const float* __restrict__ cw,   // (DI,4)
    const float* __restrict__ cb,   // (DI)
    ushort* __restrict__ out)
{
    int idx = blockIdx.x * 256 + threadIdx.x;   // over Mc*DI
    int d = idx & (DI - 1);
    int row = idx >> 10;
    int s = row & (L - 1);
    float acc = cb[d];
    #pragma unroll
    for (int j = 0; j < 4; ++j) {
        int sp = s + j - 3;
        if (sp >= 0) acc += bf2f(xc[(size_t)(row + sp - s) * DI + d]) * cw[d * 4 + j];
    }
    out[idx] = f2bf(siluf(acc));
}

// Fused selective scan. Parallel dt-phase (64x64 dt tile in LDS) + serial scan
// whose only cross-t chain is the h FMA. Block 256 = 64 d x 4 subs; one b.
__global__ __launch_bounds__(256) void scan_fused_k(
    const ushort* __restrict__ xca,  // (Mc, DI) bf16
    const float* __restrict__ xdbl,  // (Mc, 64): dtproj-in | B | C
    const ushort* __restrict__ z,    // (Mc, DI) bf16
    const float* __restrict__ dpw,   // (DI, 32)
    const float* __restrict__ dpb,   // (DI)
    const float* __restrict__ A_log, // (DI, 16)
    const float* __restrict__ Dp,    // (DI)
    ushort* __restrict__ y)          // (Mc, DI) bf16, gated output
{
    const int b = blockIdx.y;
    const int d0 = blockIdx.x * 64;
    const int tid = threadIdx.x;
    const int dl = tid >> 2, sub = tid & 3;
    const int d = d0 + dl;

    __shared__ __align__(16) float xdbl_s[64][68];
    __shared__ float dt_s[64][66];
    __shared__ __align__(16) ushort xca_s[64][72];
    __shared__ __align__(16) ushort z_s[64][72];

    float dpwr[32];
    #pragma unroll
    for (int j = 0; j < 32; ++j) dpwr[j] = dpw[d * 32 + j];
    const float dpbd = dpb[d];
    float a[4], h[4];
    #pragma unroll
    for (int i = 0; i < 4; ++i) { a[i] = -expf(A_log[d * 16 + sub * 4 + i]); h[i] = 0.f; }
    const float Dd = Dp[d];

    for (int t0 = 0; t0 < L; t0 += 64) {
        __syncthreads();   // previous tile fully consumed
        #pragma unroll
        for (int i = 0; i < 16; ++i) {
            int idx = tid + i * 256;
            int r = idx >> 6, c = idx & 63;
            xdbl_s[r][c] = xdbl[((size_t)b * L + t0 + r) * 64 + c];
        }
        #pragma unroll
        for (int i = 0; i < 4; ++i) {
            int idx = tid + i * 256;            // 0..1023
            int r = idx >> 4, c4 = (idx & 15) * 4;
            *(ushort4*)&xca_s[r][c4] = *(const ushort4*)&xca[((size_t)b * L + t0 + r) * DI + d0 + c4];
            *(ushort4*)&z_s[r][c4]   = *(const ushort4*)&z[((size_t)b * L + t0 + r) * DI + d0 + c4];
        }
        __syncthreads();
        // dt-phase: this thread computes dt for d=dl at t = sub*16+u
        #pragma unroll
        for (int u = 0; u < 16; ++u) {
            int t = sub * 16 + u;
            float s = dpbd;
            #pragma unroll
            for (int jb = 0; jb < 8; ++jb) {
                f32x4 q = *(f32x4*)&xdbl_s[t][jb * 4];
                s += q[0] * dpwr[jb*4] + q[1] * dpwr[jb*4+1] + q[2] * dpwr[jb*4+2] + q[3] * dpwr[jb*4+3];
            }
            dt_s[t][dl] = softplusf(s);
        }
        __syncthreads();
        // serial scan over the 64-t tile
        for (int tl4 = 0; tl4 < 16; ++tl4) {
            float yhold = 0.f, xhold = 0.f, zhold = 0.f;
            #pragma unroll
            for (int uu = 0; uu < 4; ++uu) {
                int tl = tl4 * 4 + uu;
                float dtv = dt_s[tl][dl];
                float xv = bf2f(xca_s[tl][dl]);
                float dtx = dtv * xv;
                f32x4 Bv = *(f32x4*)&xdbl_s[tl][32 + sub * 4];
                f32x4 Cv = *(f32x4*)&xdbl_s[tl][48 + sub * 4];
                float yp = 0.f;
                #pragma unroll
                for (int i = 0; i < 4; ++i) {
                    float dA = expf(dtv * a[i]);
                    h[i] = h[i] * dA + dtx * Bv[i];
                    yp += h[i] * Cv[i];
                }
                yp += __shfl_xor(yp, 1);
                yp += __shfl_xor(yp, 2);
                if (uu == sub) { yhold = yp; xhold = xv; zhold = bf2f(z_s[tl][dl]); }
            }
            float yout = (yhold + xhold * Dd) * siluf(zhold);
            y[((size_t)b * L + t0 + tl4 * 4 + sub) * DI + d] = f2bf(yout);
        }
    }
}

// out[row,:] = rmsnorm(A[row,:]+Bv[row,:]) * w ; one wave per row of 512.
// A bf16 (A_BF16=1) or f32; Bv f32; out f32.
template<int A_BF16>
__global__ __launch_bounds__(256) void rmsnorm_add_k(
    const void* __restrict__ A,
    const float* __restrict__ Bv,
    const float* __restrict__ w,
    float* __restrict__ out)
{
    int wid = threadIdx.x >> 6, lane = threadIdx.x & 63;
    size_t row = (size_t)blockIdx.x * 4 + wid;
    const float* br = Bv + row * D;
    float v[8]; float ss = 0.f;
    #pragma unroll
    for (int i = 0; i < 8; ++i) {
        int c = lane + i * 64;
        float av = A_BF16 ? bf2f(((const ushort*)A)[row * D + c])
                          : ((const float*)A)[row * D + c];
        float t = av + br[c];
        v[i] = t; ss += t * t;
    }
    #pragma unroll
    for (int off = 32; off; off >>= 1) ss += __shfl_xor(ss, off);
    float sc = rsqrtf(ss * (1.0f / D) + EPS);
    float* orow = out + row * D;
    #pragma unroll
    for (int i = 0; i < 8; ++i) {
        int c = lane + i * 64;
        orow[c] = v[i] * sc * w[c];
    }
}

// dec[row] = sum_d silu(enc)*bw[d] + sum_{d,j} bspl_j(enc[d])*sw[d,j]*sc[d]; one wave/row
__global__ __launch_bounds__(256) void kan_out_k(
    const float* __restrict__ enc,
    const float* __restrict__ base_w,
    const float* __restrict__ spline_w,
    const float* __restrict__ scaler,
    float* __restrict__ dec)
{
    int wid = threadIdx.x >> 6, lane = threadIdx.x & 63;
    size_t row = (size_t)blockIdx.x * 4 + wid;
    const float* er = enc + row * D;
    float sum = 0.f;
    #pragma unroll
    for (int i = 0; i < 8; ++i) {
        int dd = lane + i * 64;
        float e = er[dd];
        float bs[8]; bspline8(e, bs);
        float s2 = 0.f;
        #pragma unroll
        for (int j = 0; j < 8; ++j) s2 += bs[j] * spline_w[dd * 8 + j];
        sum += siluf(e) * base_w[dd] + s2 * scaler[dd];
    }
    #pragma unroll
    for (int off = 32; off; off >>= 1) sum += __shfl_xor(sum, off);
    if (lane == 0) dec[row] = sum;
}

// out[b,:] = rmsnorm(dec[b,:]+x[b,:]) over SEQ, weight lnx
__global__ __launch_bounds__(256) void final_norm_k(
    const float* __restrict__ dec,
    const float* __restrict__ x,
    const float* __restrict__ w,
    float* __restrict__ out)
{
    int b = blockIdx.x;
    int tid = threadIdx.x;
    __shared__ float wsum[4];
    float v[4]; float ss = 0.f;
    #pragma unroll
    for (int i = 0; i < 4; ++i) {
        int s = tid + i * 256;
        float t = dec[b * L + s] + x[b * L + s];
        v[i] = t; ss += t * t;
    }
    #pragma unroll
    for (int off = 32; off; off >>= 1) ss += __shfl_xor(ss, off);
    int lane = tid & 63, wid = tid >> 6;
    if (lane == 0) wsum[wid] = ss;
    __syncthreads();
    float total = wsum[0] + wsum[1] + wsum[2] + wsum[3];
    float sc = rsqrtf(total * (1.0f / L) + EPS);
    #pragma unroll
    for (int i = 0; i < 4; ++i) {
        int s = tid + i * 256;
        out[b * L + s] = v[i] * sc * w[s];
    }
}

extern "C" void kernel_launch(void* const* d_in, const int* in_sizes, int n_in,
                              void* d_out, int out_size, void* d_ws, size_t ws_size,
                              hipStream_t stream)
{
    const float* x    = (const float*)d_in[0];
    const float* kib  = (const float*)d_in[1];
    const float* kis  = (const float*)d_in[2];
    const float* kic  = (const float*)d_in[3];
    const float* kob  = (const float*)d_in[4];
    const float* kos  = (const float*)d_in[5];
    const float* koc  = (const float*)d_in[6];
    const float* inp  = (const float*)d_in[7];
    const float* cw   = (const float*)d_in[8];
    const float* cb   = (const float*)d_in[9];
    const float* xpw  = (const float*)d_in[10];
    const float* dpw  = (const float*)d_in[11];
    const float* dpb  = (const float*)d_in[12];
    const float* alog = (const float*)d_in[13];
    const float* dpar = (const float*)d_in[14];
    const float* opw  = (const float*)d_in[15];
    const float* w1   = (const float*)d_in[16];
    const float* b1   = (const float*)d_in[17];
    const float* w2   = (const float*)d_in[18];
    const float* b2   = (const float*)d_in[19];
    const float* lnw  = (const float*)d_in[20];
    const float* ln2  = (const float*)d_in[21];
    const float* lnx  = (const float*)d_in[22];

    // bf16 weight pool at start of workspace
    const size_t N_INP = (size_t)4 * 2048 * 512;   // 4,194,304
    const size_t N_XPW = (size_t)4 * 64 * 1024;    //   262,144
    const size_t N_OPW = (size_t)4 * 512 * 1024;   // 2,097,152
    const size_t N_W1  = (size_t)1024 * 512;       //   524,288
    const size_t N_W2  = (size_t)512 * 1024;       //   524,288
    const size_t WB_ELTS = N_INP + N_XPW + N_OPW + N_W1 + N_W2;
    const size_t WB_BYTES = WB_ELTS * 2;           // 15,204,352 (16B-aligned)

    ushort* wb_inp = (ushort*)d_ws;
    ushort* wb_xpw = wb_inp + N_INP;
    ushort* wb_opw = wb_xpw + N_XPW;
    ushort* wb_w1  = wb_opw + N_OPW;
    ushort* wb_w2  = wb_w1 + N_W1;

    // per-row bytes: h0(2048)+hcur(2048)+xdbl(256)+dec(4)+3 bf16 bufs(6144) = 10500
    const size_t PER_ROW = 10500;
    int C = 32;
    while (C > 1 && (size_t)C * 1024 * PER_ROW + WB_BYTES > ws_size) C >>= 1;
    if ((size_t)C * 1024 * PER_ROW + WB_BYTES > ws_size) return;

    cvt_bf16_k<<<2048, 256, 0, stream>>>(inp, wb_inp, (int)N_INP);
    cvt_bf16_k<<<1024, 256, 0, stream>>>(xpw, wb_xpw, (int)N_XPW);
    cvt_bf16_k<<<2048, 256, 0, stream>>>(opw, wb_opw, (int)N_OPW);
    cvt_bf16_k<<<1024, 256, 0, stream>>>(w1, wb_w1, (int)N_W1);
    cvt_bf16_k<<<1024, 256, 0, stream>>>(w2, wb_w2, (int)N_W2);

    for (int b0 = 0; b0 < 32; b0 += C) {
        const size_t Mc = (size_t)C * L;
        float* fbase = (float*)((char*)d_ws + WB_BYTES);
        float* h0   = fbase;              // Mc*512 f32
        float* hcur = h0 + Mc * D;        // Mc*512 f32
        float* xdbl = hcur + Mc * D;      // Mc*64 f32
        float* dec  = xdbl + Mc * 64;     // Mc f32
        ushort* bufA = (ushort*)(dec + Mc);          // Mc*1024 bf16: xc -> y
        ushort* bufB = bufA + Mc * DI;               // Mc*1024 bf16: xca -> hm | mlp
        ushort* bufZ = bufB + Mc * DI;               // Mc*1024 bf16: z -> hid

        kan_in_k<<<(unsigned)Mc, 256, 0, stream>>>(x + (size_t)b0 * L, kib, kis, kic, h0);

        for (int l = 0; l < 4; ++l) {
            const float* hin = (l == 0) ? h0 : hcur;
            const ushort* wb_inp_l = wb_inp + (size_t)l * 2048 * 512;
            // xc = hin @ Wxc^T -> bufA ; z = hin @ Wz^T -> bufZ   (f32 A, bf16 out)
            gemm_mfma_k<0,1,1><<<dim3(16, (unsigned)(Mc / 128)), 256, 0, stream>>>(
                hin, D, wb_inp_l, nullptr, bufA, (int)Mc, DI, D);
            gemm_mfma_k<0,1,1><<<dim3(16, (unsigned)(Mc / 128)), 256, 0, stream>>>(
                hin, D, wb_inp_l + (size_t)DI * D, nullptr, bufZ, (int)Mc, DI, D);
            // xca = silu(causal_conv(xc)) -> bufB
            conv_silu_k<<<(unsigned)((Mc * DI) / 256), 256, 0, stream>>>(
                bufA, cw + (size_t)l * DI * 4, cb + (size_t)l * DI, bufB);
            // xdbl = xca @ x_proj^T (Mc, 64) f32
            gemm_mfma_k<0,0,0><<<dim3(1, (unsigned)(Mc / 128)), 256, 0, stream>>>(
                bufB, DI, wb_xpw + (size_t)l * 64 * DI, nullptr, xdbl, (int)Mc, 64, DI);
            // fused scan (dt-proj + scan + D-skip + silu(z) gate) -> bufA
            scan_fused_k<<<dim3(16, C), 256, 0, stream>>>(
                bufB, xdbl, bufZ,
                dpw + (size_t)l * DI * 32, dpb + (size_t)l * DI,
                alog + (size_t)l * DI * 16, dpar + (size_t)l * DI, bufA);
            // hm = y @ out_proj^T (Mc, 512) -> bufB
            gemm_mfma_k<0,0,1><<<dim3(8, (unsigned)(Mc / 128)), 256, 0, stream>>>(
                bufA, DI, wb_opw + (size_t)l * D * DI, nullptr, bufB, (int)Mc, D, DI);
            // hid = gelu(hm @ w1^T + b1) (Mc, 1024) -> bufZ
            gemm_mfma_k<2,0,1><<<dim3(16, (unsigned)(Mc / 128)), 256, 0, stream>>>(
                bufB, D, wb_w1, b1, bufZ, (int)Mc, DI, D);
            // mlp = gelu(hid @ w2^T + b2) (Mc, 512) -> bufB second half
            gemm_mfma_k<2,0,1><<<dim3(8, (unsigned)(Mc / 128)), 256, 0, stream>>>(
                bufZ, DI, wb_w2, b2, bufB + Mc * D, (int)Mc, D, DI);
            // hcur = rmsnorm(mlp + hin) * ln_w  (f32 out)
            rmsnorm_add_k<1><<<(unsigned)(Mc / 4), 256, 0, stream>>>(bufB + Mc * D, hin, lnw, hcur);
        }
        // enc = rmsnorm(hcur + h0) * ln2  (in place, f32)
        rmsnorm_add_k<0><<<(unsigned)(Mc / 4), 256, 0, stream>>>(hcur, h0, ln2, hcur);
        kan_out_k<<<(unsigned)(Mc / 4), 256, 0, stream>>>(hcur, kob, kos, koc, dec);
        final_norm_k<<<C, 256, 0, stream>>>(dec, x + (size_t)b0 * L, lnx, (float*)d_out + (size_t)b0 * L);
    }
}

// Round 5
// 5402.570 us; speedup vs baseline: 5.6618x; 1.2450x over previous
//
#include <hip/hip_runtime.h>

constexpr int L = 1024;
constexpr int D = 512;      // d_model
constexpr int DI = 1024;    // d_inner
constexpr float EPS = 1.1920929e-07f;

typedef short bf16x8 __attribute__((ext_vector_type(8)));
typedef float f32x4 __attribute__((ext_vector_type(4)));

__device__ __forceinline__ float siluf(float x) { return x / (1.0f + expf(-x)); }
__device__ __forceinline__ float geluf(float x) { return 0.5f * x * (1.0f + erff(x * 0.7071067811865476f)); }
__device__ __forceinline__ float softplusf(float x) { return fmaxf(x, 0.0f) + log1pf(expf(-fabsf(x))); }

__device__ __forceinline__ float bf2f(ushort h) {
    unsigned u = ((unsigned)h) << 16;
    return __uint_as_float(u);
}
__device__ __forceinline__ ushort f2bf(float f) {
    unsigned u = __float_as_uint(f);
    u = (u + 0x7fffu + ((u >> 16) & 1u)) >> 16;
    return (ushort)u;
}

__device__ __forceinline__ void async_copy16(const void* g, void* l) {
    __builtin_amdgcn_global_load_lds(
        (const __attribute__((address_space(1))) void*)g,
        (__attribute__((address_space(3))) void*)l, 16, 0, 0);
}

// quad (4-lane) sum via DPP quad_perm — no LDS traffic
__device__ __forceinline__ float quad_reduce(float v) {
    int t = __builtin_amdgcn_update_dpp(0, __float_as_int(v), 0xB1, 0xF, 0xF, true);
    v += __int_as_float(t);
    t = __builtin_amdgcn_update_dpp(0, __float_as_int(v), 0x4E, 0xF, 0xF, true);
    v += __int_as_float(t);
    return v;
}

// 8 cubic B-spline bases on the efficient-kan grid (GRID_SIZE=5, order 3)
__device__ __forceinline__ void bspline8(float x, float* o) {
    const float h = 0.4f;
    float g[12];
    #pragma unroll
    for (int j = 0; j < 12; ++j) g[j] = (float)(j - 3) * h - 1.0f;
    float b[11];
    #pragma unroll
    for (int j = 0; j < 11; ++j) b[j] = (x >= g[j] && x < g[j + 1]) ? 1.0f : 0.0f;
    #pragma unroll
    for (int k = 1; k <= 3; ++k) {
        #pragma unroll
        for (int j = 0; j < 11 - k; ++j) {
            float d1 = g[j + k] - g[j];
            float d2 = g[j + k + 1] - g[j + 1];
            b[j] = (x - g[j]) / d1 * b[j] + (g[j + k + 1] - x) / d2 * b[j + 1];
        }
    }
    #pragma unroll
    for (int j = 0; j < 8; ++j) o[j] = b[j];
}

// fp32 -> bf16 convert (weights), grid-stride
__global__ __launch_bounds__(256) void cvt_bf16_k(const float* __restrict__ s,
                                                  ushort* __restrict__ d, int n) {
    for (int i = blockIdx.x * 256 + threadIdx.x; i < n; i += gridDim.x * 256)
        d[i] = f2bf(s[i]);
}

// m97-style MFMA GEMM: 128x128 tile, BK=64, 4 waves, global_load_lds staging.
// A bf16 (M, lda) row-major; W bf16 (N, K) row-major; C (M, ldc): bf16 or f32.
// ACT: 0 none, 2 gelu
template<int ACT, int OUT_BF16>
__global__ __launch_bounds__(256) void gemm128_k(
    const ushort* __restrict__ A, int lda,
    const ushort* __restrict__ W,
    const float* __restrict__ bias,
    void* __restrict__ Cv, int ldc,
    int M, int N, int K)
{
    __shared__ __align__(16) ushort As[128 * 64];
    __shared__ __align__(16) ushort Bs[128 * 64];
    const int tid = threadIdx.x;
    const int w = tid >> 6, lane = tid & 63;
    const int m0 = blockIdx.y * 128, n0 = blockIdx.x * 128;
    const int lr = lane & 15, lh = lane >> 4;
    const int srow = lane >> 3;        // 0..7 within 8-row stripe
    const int scol = (lane & 7) * 8;   // element col offset
    f32x4 acc[2][8] = {};

    for (int k0 = 0; k0 < K; k0 += 64) {
        #pragma unroll
        for (int i = 0; i < 4; ++i) {
            int row = w * 32 + i * 8;  // wave-uniform stripe base
            const ushort* ga = A + (size_t)(m0 + row + srow) * lda + k0 + scol;
            async_copy16(ga, &As[row * 64]);
            const ushort* gb = W + (size_t)(n0 + row + srow) * K + k0 + scol;
            async_copy16(gb, &Bs[row * 64]);
        }
        __syncthreads();
        #pragma unroll
        for (int kk = 0; kk < 2; ++kk) {
            bf16x8 af[2];
            #pragma unroll
            for (int mi = 0; mi < 2; ++mi)
                af[mi] = *(const bf16x8*)&As[(w * 32 + mi * 16 + lr) * 64 + kk * 32 + lh * 8];
            #pragma unroll
            for (int nj = 0; nj < 8; ++nj) {
                bf16x8 bfr = *(const bf16x8*)&Bs[(nj * 16 + lr) * 64 + kk * 32 + lh * 8];
                acc[0][nj] = __builtin_amdgcn_mfma_f32_16x16x32_bf16(af[0], bfr, acc[0][nj], 0, 0, 0);
                acc[1][nj] = __builtin_amdgcn_mfma_f32_16x16x32_bf16(af[1], bfr, acc[1][nj], 0, 0, 0);
            }
        }
        __syncthreads();
    }

    #pragma unroll
    for (int mi = 0; mi < 2; ++mi) {
        int rbase = m0 + w * 32 + mi * 16 + lh * 4;
        #pragma unroll
        for (int nj = 0; nj < 8; ++nj) {
            int col = n0 + nj * 16 + lr;
            float bv = bias ? bias[col] : 0.0f;
            #pragma unroll
            for (int r = 0; r < 4; ++r) {
                float v = acc[mi][nj][r] + bv;
                if (ACT == 2) v = geluf(v);
                if (OUT_BF16) ((ushort*)Cv)[(size_t)(rbase + r) * ldc + col] = f2bf(v);
                else          ((float*)Cv)[(size_t)(rbase + r) * ldc + col] = v;
            }
        }
    }
}

// Small-N MFMA GEMM (tile 128x64, K-step 32), reg staging.
// A: fp32 (A_F32=1) or bf16; W bf16 (N,K); C dense (ldc=N). ACT: 0 none, 3 softplus.
template<int ACT, int A_F32, int OUT_BF16>
__global__ __launch_bounds__(256) void gemm_mfma_k(
    const void* __restrict__ Av, int lda,
    const ushort* __restrict__ W,
    const float* __restrict__ bias,
    void* __restrict__ Cv,
    int M, int N, int K)
{
    __shared__ __align__(16) ushort As[128][40];
    __shared__ __align__(16) ushort Bs[64][40];
    const int tid = threadIdx.x;
    const int m0 = blockIdx.y * 128, n0 = blockIdx.x * 64;
    const int w = tid >> 6, lane = tid & 63;
    const int lr = lane & 15, lh = lane >> 4;
    const int arow = tid >> 1, akoff = (tid & 1) * 16;
    const int brow = tid >> 2, bkoff = (tid & 3) * 8;

    f32x4 acc[2][4] = {};

    for (int k0 = 0; k0 < K; k0 += 32) {
        if (A_F32) {
            const float* Ar = (const float*)Av + (size_t)(m0 + arow) * lda + k0 + akoff;
            f32x4 q0 = *(const f32x4*)(Ar);
            f32x4 q1 = *(const f32x4*)(Ar + 4);
            f32x4 q2 = *(const f32x4*)(Ar + 8);
            f32x4 q3 = *(const f32x4*)(Ar + 12);
            ushort* dst = &As[arow][akoff];
            dst[0] = f2bf(q0[0]); dst[1] = f2bf(q0[1]); dst[2] = f2bf(q0[2]); dst[3] = f2bf(q0[3]);
            dst[4] = f2bf(q1[0]); dst[5] = f2bf(q1[1]); dst[6] = f2bf(q1[2]); dst[7] = f2bf(q1[3]);
            dst[8] = f2bf(q2[0]); dst[9] = f2bf(q2[1]); dst[10] = f2bf(q2[2]); dst[11] = f2bf(q2[3]);
            dst[12] = f2bf(q3[0]); dst[13] = f2bf(q3[1]); dst[14] = f2bf(q3[2]); dst[15] = f2bf(q3[3]);
        } else {
            const ushort* Ar = (const ushort*)Av + (size_t)(m0 + arow) * lda + k0 + akoff;
            *(bf16x8*)&As[arow][akoff] = *(const bf16x8*)Ar;
            *(bf16x8*)&As[arow][akoff + 8] = *(const bf16x8*)(Ar + 8);
        }
        const ushort* Wr = W + (size_t)(n0 + brow) * K + k0 + bkoff;
        *(bf16x8*)&Bs[brow][bkoff] = *(const bf16x8*)Wr;
        __syncthreads();

        bf16x8 aF0 = *(bf16x8*)&As[w * 32 + lr][lh * 8];
        bf16x8 aF1 = *(bf16x8*)&As[w * 32 + 16 + lr][lh * 8];
        bf16x8 bF0 = *(bf16x8*)&Bs[lr][lh * 8];
        bf16x8 bF1 = *(bf16x8*)&Bs[16 + lr][lh * 8];
        bf16x8 bF2 = *(bf16x8*)&Bs[32 + lr][lh * 8];
        bf16x8 bF3 = *(bf16x8*)&Bs[48 + lr][lh * 8];
        acc[0][0] = __builtin_amdgcn_mfma_f32_16x16x32_bf16(aF0, bF0, acc[0][0], 0, 0, 0);
        acc[0][1] = __builtin_amdgcn_mfma_f32_16x16x32_bf16(aF0, bF1, acc[0][1], 0, 0, 0);
        acc[0][2] = __builtin_amdgcn_mfma_f32_16x16x32_bf16(aF0, bF2, acc[0][2], 0, 0, 0);
        acc[0][3] = __builtin_amdgcn_mfma_f32_16x16x32_bf16(aF0, bF3, acc[0][3], 0, 0, 0);
        acc[1][0] = __builtin_amdgcn_mfma_f32_16x16x32_bf16(aF1, bF0, acc[1][0], 0, 0, 0);
        acc[1][1] = __builtin_amdgcn_mfma_f32_16x16x32_bf16(aF1, bF1, acc[1][1], 0, 0, 0);
        acc[1][2] = __builtin_amdgcn_mfma_f32_16x16x32_bf16(aF1, bF2, acc[1][2], 0, 0, 0);
        acc[1][3] = __builtin_amdgcn_mfma_f32_16x16x32_bf16(aF1, bF3, acc[1][3], 0, 0, 0);
        __syncthreads();
    }

    #pragma unroll
    for (int mi = 0; mi < 2; ++mi) {
        #pragma unroll
        for (int nj = 0; nj < 4; ++nj) {
            int col = n0 + nj * 16 + lr;
            float bv = bias ? bias[col] : 0.0f;
            int rbase = m0 + w * 32 + mi * 16 + lh * 4;
            #pragma unroll
            for (int r = 0; r < 4; ++r) {
                float v = acc[mi][nj][r] + bv;
                if (ACT == 3) v = softplusf(v);
                if (OUT_BF16) ((ushort*)Cv)[(size_t)(rbase + r) * N + col] = f2bf(v);
                else          ((float*)Cv)[(size_t)(rbase + r) * N + col] = v;
            }
        }
    }
}

// h0[row,d] (f32 + bf16 shadow)
__global__ __launch_bounds__(256) void kan_in_k(
    const float* __restrict__ x,
    const float* __restrict__ base_w,
    const float* __restrict__ spline_w,
    const float* __restrict__ scaler,
    float* __restrict__ h0,
    ushort* __restrict__ h0b)
{
    int row = blockIdx.x;
    float u = x[row];
    float su = siluf(u);
    float bs[8]; bspline8(u, bs);
    for (int d = threadIdx.x; d < D; d += 256) {
        float s2 = 0.f;
        #pragma unroll
        for (int j = 0; j < 8; ++j) s2 += bs[j] * spline_w[d * 8 + j];
        float v = su * base_w[d] + s2 * scaler[d];
        h0[(size_t)row * D + d] = v;
        h0b[(size_t)row * D + d] = f2bf(v);
    }
}

// causal depthwise conv (k=4) + bias + silu; xc in xz (stride 2048), out stride 1024
__global__ __launch_bounds__(256) void conv_silu_k(
    const ushort* __restrict__ xz,
    const float* __restrict__ cw,   // (DI,4)
    const float* __restrict__ cb,   // (DI)
    ushort* __restrict__ out)
{
    int idx = blockIdx.x * 256 + threadIdx.x;   // over Mc*DI
    int d = idx & (DI - 1);
    int row = idx >> 10;
    int s = row & (L - 1);
    float acc = cb[d];
    #pragma unroll
    for (int j = 0; j < 4; ++j) {
        int sp = s + j - 3;
        if (sp >= 0) acc += bf2f(xz[(size_t)(row + sp - s) * 2048 + d]) * cw[d * 4 + j];
    }
    out[idx] = f2bf(siluf(acc));
}

// Selective scan: dt precomputed (bf16). Block 256 = 64 d x 4 subs; one b per blockIdx.y.
// z read at stride 2048 (xz second half); y written at stride 2048 (xz first half).
__global__ __launch_bounds__(256) void scan_fused_k(
    const ushort* __restrict__ xca,  // (Mc, 1024) bf16
    const float* __restrict__ xdbl,  // (Mc, 64): . | B | C
    const ushort* __restrict__ z,    // stride 2048
    const ushort* __restrict__ dt,   // (Mc, 1024) bf16
    const float* __restrict__ A_log, // (DI, 16)
    const float* __restrict__ Dp,    // (DI)
    ushort* __restrict__ y)          // stride 2048
{
    const int b = blockIdx.y;
    const int d0 = blockIdx.x * 64;
    const int tid = threadIdx.x;
    const int dl = tid >> 2, sub = tid & 3;
    const int d = d0 + dl;

    __shared__ __align__(16) float  BC_s[64][36];
    __shared__ __align__(16) ushort dt_s[64][72];
    __shared__ __align__(16) ushort xca_s[64][72];
    __shared__ __align__(16) ushort z_s[64][72];

    float a[4], h[4];
    #pragma unroll
    for (int i = 0; i < 4; ++i) { a[i] = -expf(A_log[d * 16 + sub * 4 + i]); h[i] = 0.f; }
    const float Dd = Dp[d];

    for (int t0 = 0; t0 < L; t0 += 64) {
        __syncthreads();   // previous tile fully consumed
        #pragma unroll
        for (int i = 0; i < 8; ++i) {
            int idx = tid + i * 256;
            int r = idx >> 5, c = idx & 31;
            BC_s[r][c] = xdbl[((size_t)b * L + t0 + r) * 64 + 32 + c];
        }
        #pragma unroll
        for (int i = 0; i < 4; ++i) {
            int idx = tid + i * 256;            // 0..1023
            int r = idx >> 4, c4 = (idx & 15) * 4;
            size_t grow = (size_t)b * L + t0 + r;
            *(ushort4*)&xca_s[r][c4] = *(const ushort4*)&xca[grow * 1024 + d0 + c4];
            *(ushort4*)&dt_s[r][c4]  = *(const ushort4*)&dt[grow * 1024 + d0 + c4];
            *(ushort4*)&z_s[r][c4]   = *(const ushort4*)&z[grow * 2048 + d0 + c4];
        }
        __syncthreads();

        for (int tl4 = 0; tl4 < 16; ++tl4) {
            float yhold = 0.f, xhold = 0.f, zhold = 0.f;
            #pragma unroll
            for (int uu = 0; uu < 4; ++uu) {
                int tl = tl4 * 4 + uu;
                float dtv = bf2f(dt_s[tl][dl]);
                float xv  = bf2f(xca_s[tl][dl]);
                float dtx = dtv * xv;
                f32x4 Bv = *(const f32x4*)&BC_s[tl][sub * 4];
                f32x4 Cvv = *(const f32x4*)&BC_s[tl][16 + sub * 4];
                float yp = 0.f;
                #pragma unroll
                for (int i = 0; i < 4; ++i) {
                    float dA = expf(dtv * a[i]);
                    h[i] = h[i] * dA + dtx * Bv[i];
                    yp += h[i] * Cvv[i];
                }
                yp = quad_reduce(yp);
                if (uu == sub) { yhold = yp; xhold = xv; zhold = bf2f(z_s[tl][dl]); }
            }
            float yout = (yhold + xhold * Dd) * siluf(zhold);
            y[((size_t)b * L + t0 + tl4 * 4 + sub) * 2048 + d] = f2bf(yout);
        }
    }
}

// out[row,:] = rmsnorm(A[row,:]+Bv[row,:]) * w ; f32 out + bf16 shadow
template<int A_BF16>
__global__ __launch_bounds__(256) void rmsnorm_add_k(
    const void* __restrict__ A,
    const float* __restrict__ Bv,
    const float* __restrict__ w,
    float* __restrict__ out,
    ushort* __restrict__ outb)
{
    int wid = threadIdx.x >> 6, lane = threadIdx.x & 63;
    size_t row = (size_t)blockIdx.x * 4 + wid;
    const float* br = Bv + row * D;
    float v[8]; float ss = 0.f;
    #pragma unroll
    for (int i = 0; i < 8; ++i) {
        int c = lane + i * 64;
        float av = A_BF16 ? bf2f(((const ushort*)A)[row * D + c])
                          : ((const float*)A)[row * D + c];
        float t = av + br[c];
        v[i] = t; ss += t * t;
    }
    #pragma unroll
    for (int off = 32; off; off >>= 1) ss += __shfl_xor(ss, off);
    float sc = rsqrtf(ss * (1.0f / D) + EPS);
    #pragma unroll
    for (int i = 0; i < 8; ++i) {
        int c = lane + i * 64;
        float o = v[i] * sc * w[c];
        out[row * D + c] = o;
        outb[row * D + c] = f2bf(o);
    }
}

// dec[row] = KAN-out over enc row; one wave per row
__global__ __launch_bounds__(256) void kan_out_k(
    const float* __restrict__ enc,
    const float* __restrict__ base_w,
    const float* __restrict__ spline_w,
    const float* __restrict__ scaler,
    float* __restrict__ dec)
{
    int wid = threadIdx.x >> 6, lane = threadIdx.x & 63;
    size_t row = (size_t)blockIdx.x * 4 + wid;
    const float* er = enc + row * D;
    float sum = 0.f;
    #pragma unroll
    for (int i = 0; i < 8; ++i) {
        int dd = lane + i * 64;
        float e = er[dd];
        float bs[8]; bspline8(e, bs);
        float s2 = 0.f;
        #pragma unroll
        for (int j = 0; j < 8; ++j) s2 += bs[j] * spline_w[dd * 8 + j];
        sum += siluf(e) * base_w[dd] + s2 * scaler[dd];
    }
    #pragma unroll
    for (int off = 32; off; off >>= 1) sum += __shfl_xor(sum, off);
    if (lane == 0) dec[row] = sum;
}

// out[b,:] = rmsnorm(dec[b,:]+x[b,:]) over SEQ, weight lnx
__global__ __launch_bounds__(256) void final_norm_k(
    const float* __restrict__ dec,
    const float* __restrict__ x,
    const float* __restrict__ w,
    float* __restrict__ out)
{
    int b = blockIdx.x;
    int tid = threadIdx.x;
    __shared__ float wsum[4];
    float v[4]; float ss = 0.f;
    #pragma unroll
    for (int i = 0; i < 4; ++i) {
        int s = tid + i * 256;
        float t = dec[b * L + s] + x[b * L + s];
        v[i] = t; ss += t * t;
    }
    #pragma unroll
    for (int off = 32; off; off >>= 1) ss += __shfl_xor(ss, off);
    int lane = tid & 63, wid = tid >> 6;
    if (lane == 0) wsum[wid] = ss;
    __syncthreads();
    float total = wsum[0] + wsum[1] + wsum[2] + wsum[3];
    float sc = rsqrtf(total * (1.0f / L) + EPS);
    #pragma unroll
    for (int i = 0; i < 4; ++i) {
        int s = tid + i * 256;
        out[b * L + s] = v[i] * sc * w[s];
    }
}

extern "C" void kernel_launch(void* const* d_in, const int* in_sizes, int n_in,
                              void* d_out, int out_size, void* d_ws, size_t ws_size,
                              hipStream_t stream)
{
    const float* x    = (const float*)d_in[0];
    const float* kib  = (const float*)d_in[1];
    const float* kis  = (const float*)d_in[2];
    const float* kic  = (const float*)d_in[3];
    const float* kob  = (const float*)d_in[4];
    const float* kos  = (const float*)d_in[5];
    const float* koc  = (const float*)d_in[6];
    const float* inp  = (const float*)d_in[7];
    const float* cw   = (const float*)d_in[8];
    const float* cb   = (const float*)d_in[9];
    const float* xpw  = (const float*)d_in[10];
    const float* dpw  = (const float*)d_in[11];
    const float* dpb  = (const float*)d_in[12];
    const float* alog = (const float*)d_in[13];
    const float* dpar = (const float*)d_in[14];
    const float* opw  = (const float*)d_in[15];
    const float* w1   = (const float*)d_in[16];
    const float* b1   = (const float*)d_in[17];
    const float* w2   = (const float*)d_in[18];
    const float* b2   = (const float*)d_in[19];
    const float* lnw  = (const float*)d_in[20];
    const float* ln2  = (const float*)d_in[21];
    const float* lnx  = (const float*)d_in[22];

    // bf16 weight pool
    const size_t N_INP = (size_t)4 * 2048 * 512;
    const size_t N_XPW = (size_t)4 * 64 * 1024;
    const size_t N_OPW = (size_t)4 * 512 * 1024;
    const size_t N_W1  = (size_t)1024 * 512;
    const size_t N_W2  = (size_t)512 * 1024;
    const size_t N_DPW = (size_t)4 * 1024 * 32;
    const size_t WB_BYTES = (N_INP + N_XPW + N_OPW + N_W1 + N_W2 + N_DPW) * 2;

    ushort* wb_inp = (ushort*)d_ws;
    ushort* wb_xpw = wb_inp + N_INP;
    ushort* wb_opw = wb_xpw + N_XPW;
    ushort* wb_w1  = wb_opw + N_OPW;
    ushort* wb_w2  = wb_w1 + N_W1;
    ushort* wb_dpw = wb_w2 + N_W2;

    // per-row bytes: f32(512+512+64+1)=4356 + bf16(2048+1024+1024+512+512)=10240 -> 14596
    const size_t PER_ROW = 14596;
    int C = 32;
    while (C > 1 && (size_t)C * 1024 * PER_ROW + WB_BYTES > ws_size) C >>= 1;
    if ((size_t)C * 1024 * PER_ROW + WB_BYTES > ws_size) return;

    cvt_bf16_k<<<2048, 256, 0, stream>>>(inp, wb_inp, (int)N_INP);
    cvt_bf16_k<<<1024, 256, 0, stream>>>(xpw, wb_xpw, (int)N_XPW);
    cvt_bf16_k<<<2048, 256, 0, stream>>>(opw, wb_opw, (int)N_OPW);
    cvt_bf16_k<<<1024, 256, 0, stream>>>(w1, wb_w1, (int)N_W1);
    cvt_bf16_k<<<1024, 256, 0, stream>>>(w2, wb_w2, (int)N_W2);
    cvt_bf16_k<<<512, 256, 0, stream>>>(dpw, wb_dpw, (int)N_DPW);

    for (int b0 = 0; b0 < 32; b0 += C) {
        const size_t Mc = (size_t)C * L;
        float* fbase = (float*)((char*)d_ws + WB_BYTES);
        float* h0   = fbase;              // Mc*512 f32
        float* hcur = h0 + Mc * D;        // Mc*512 f32
        float* xdbl = hcur + Mc * D;      // Mc*64 f32
        float* dec  = xdbl + Mc * 64;     // Mc f32
        ushort* xz    = (ushort*)(dec + Mc);   // Mc*2048: xc|z -> y|hid
        ushort* bufB  = xz + Mc * 2048;        // Mc*1024: xca -> hm(512) | mlp(512)
        ushort* bufD  = bufB + Mc * 1024;      // Mc*1024: dt
        ushort* h0b   = bufD + Mc * 1024;      // Mc*512
        ushort* hcurb = h0b + Mc * D;          // Mc*512

        kan_in_k<<<(unsigned)Mc, 256, 0, stream>>>(x + (size_t)b0 * L, kib, kis, kic, h0, h0b);

        for (int l = 0; l < 4; ++l) {
            const float* hin = (l == 0) ? h0 : hcur;
            const ushort* hinb = (l == 0) ? h0b : hcurb;
            const ushort* wb_inp_l = wb_inp + (size_t)l * 2048 * 512;
            // xz = hin @ in_proj^T  (Mc, 2048)
            gemm128_k<0,1><<<dim3(16, (unsigned)(Mc / 128)), 256, 0, stream>>>(
                hinb, D, wb_inp_l, nullptr, xz, 2048, (int)Mc, 2048, D);
            // xca = silu(causal_conv(xz[:, :1024])) -> bufB
            conv_silu_k<<<(unsigned)((Mc * DI) / 256), 256, 0, stream>>>(
                xz, cw + (size_t)l * DI * 4, cb + (size_t)l * DI, bufB);
            // xdbl = xca @ x_proj^T (Mc, 64) f32
            gemm_mfma_k<0,0,0><<<dim3(1, (unsigned)(Mc / 128)), 256, 0, stream>>>(
                bufB, DI, wb_xpw + (size_t)l * 64 * DI, nullptr, xdbl, (int)Mc, 64, DI);
            // dt = softplus(xdbl[:, :32] @ dt_proj^T + dpb) -> bufD bf16
            gemm_mfma_k<3,1,1><<<dim3(16, (unsigned)(Mc / 128)), 256, 0, stream>>>(
                xdbl, 64, wb_dpw + (size_t)l * 1024 * 32, dpb + (size_t)l * DI, bufD, (int)Mc, DI, 32);
            // scan (+ D-skip + silu(z) gate) -> y into xz first half (stride 2048)
            scan_fused_k<<<dim3(16, C), 256, 0, stream>>>(
                bufB, xdbl, xz + 1024, bufD,
                alog + (size_t)l * DI * 16, dpar + (size_t)l * DI, xz);
            // hm = y @ out_proj^T (Mc, 512) -> bufB (dense 512)
            gemm128_k<0,1><<<dim3(4, (unsigned)(Mc / 128)), 256, 0, stream>>>(
                xz, 2048, wb_opw + (size_t)l * D * DI, nullptr, bufB, 512, (int)Mc, 512, DI);
            // hid = gelu(hm @ w1^T + b1) (Mc, 1024) -> xz second half (ldc 2048)
            gemm128_k<2,1><<<dim3(8, (unsigned)(Mc / 128)), 256, 0, stream>>>(
                bufB, 512, wb_w1, b1, xz + 1024, 2048, (int)Mc, 1024, D);
            // mlp = gelu(hid @ w2^T + b2) (Mc, 512) -> bufB second half (dense 512)
            gemm128_k<2,1><<<dim3(4, (unsigned)(Mc / 128)), 256, 0, stream>>>(
                xz + 1024, 2048, wb_w2, b2, bufB + Mc * 512, 512, (int)Mc, 512, DI);
            // hcur = rmsnorm(mlp + hin) * ln_w  (+ bf16 shadow)
            rmsnorm_add_k<1><<<(unsigned)(Mc / 4), 256, 0, stream>>>(
                bufB + Mc * 512, hin, lnw, hcur, hcurb);
        }
        // enc = rmsnorm(hcur + h0) * ln2 (in place; bf shadow unused)
        rmsnorm_add_k<0><<<(unsigned)(Mc / 4), 256, 0, stream>>>(hcur, h0, ln2, hcur, hcurb);
        kan_out_k<<<(unsigned)(Mc / 4), 256, 0, stream>>>(hcur, kob, kos, koc, dec);
        final_norm_k<<<C, 256, 0, stream>>>(dec, x + (size_t)b0 * L, lnx, (float*)d_out + (size_t)b0 * L);
    }
}